// Round 1
// baseline (299.383 us; speedup 1.0000x reference)
//
#include <hip/hip_runtime.h>
#include <hip/hip_bf16.h>

typedef _Float16 h8_t __attribute__((ext_vector_type(8)));
typedef float f4_t __attribute__((ext_vector_type(4)));

#define HWPX 65536
#define QSTR 72  // LDS row stride in halves (64 + 8 pad -> 144B rows, breaks bank conflicts)

// ---------------- Kernel 1: L2-normalize src pixels + keypoints to f16 ----------------
__global__ __launch_bounds__(256) void k_norm(
    const float* __restrict__ dense, const float* __restrict__ kdesc,
    _Float16* __restrict__ Qn, _Float16* __restrict__ Kn,
    float* __restrict__ partials)
{
    int tid = threadIdx.x;
    int bid = blockIdx.x;
    if (bid < 512) {
        // dense source pixels: 2 batches x 65536 pixels, frame = b*4
        int pid = bid * 256 + tid;          // 0..131071
        int b = pid >> 16, m = pid & 65535;
        const float* src = dense + ((size_t)(b * 4) * 64) * HWPX + m;
        float v[64];
        float ss = 0.f;
#pragma unroll
        for (int c = 0; c < 64; ++c) { float x = src[(size_t)c * HWPX]; v[c] = x; ss += x * x; }
        float inv = 1.0f / fmaxf(sqrtf(ss), 1e-12f);
        h8_t* dst = (h8_t*)(Kn + (size_t)pid * 64);
#pragma unroll
        for (int i = 0; i < 8; ++i) {
            h8_t hv;
#pragma unroll
            for (int j = 0; j < 8; ++j) hv[j] = (_Float16)(v[i * 8 + j] * inv);
            dst[i] = hv;
        }
    } else {
        // target keypoints: q = b*768 + w*256 + n, frame = b*4 + 1 + w
        int q = (bid - 512) * 256 + tid;    // 0..1535
        int b = q / 768;
        int w = (q >> 8) % 3;
        int n = q & 255;
        int frame = b * 4 + 1 + w;
        const float* src = kdesc + (size_t)frame * 64 * 256 + n;
        float v[64]; float ss = 0.f;
#pragma unroll
        for (int c = 0; c < 64; ++c) { float x = src[c * 256]; v[c] = x; ss += x * x; }
        float inv = 1.0f / fmaxf(sqrtf(ss), 1e-12f);
        h8_t* dst = (h8_t*)(Qn + (size_t)q * 64);
#pragma unroll
        for (int i = 0; i < 8; ++i) {
            h8_t hv;
#pragma unroll
            for (int j = 0; j < 8; ++j) hv[j] = (_Float16)(v[i * 8 + j] * inv);
            dst[i] = hv;
        }
        partials[q * 3 + 0] = 0.f;
        partials[q * 3 + 1] = 0.f;
        partials[q * 3 + 2] = 0.f;
    }
}

// ---------------- Kernel 2: attention with fixed-offset exp (no max pass) ----------------
// grid: (128 key-chunks of 512, 3 query-groups of 256, 2 batches), block 256 (4 waves)
// Each wave owns 64 queries (4 tiles of 16). Per 16-key MFMA tile: score = cos,
// w = exp2(144.2695*cos - 144.2695) == exp((cos/0.01 - 100)); accumulate l, sum(w*u), sum(w*v).
__global__ __launch_bounds__(256) void k_attn(
    const _Float16* __restrict__ Qn, const _Float16* __restrict__ Kn,
    float* __restrict__ partials)
{
    __shared__ _Float16 Qs[256 * QSTR];
    __shared__ _Float16 Ks[64 * QSTR];

    int tid = threadIdx.x;
    int chunk = blockIdx.x, qg = blockIdx.y, b = blockIdx.z;
    int kbase = chunk * 512;
    int qbase = b * 768 + qg * 256;

    // stage Q tile (256 queries x 64 ch f16)
    {
        const h8_t* src = (const h8_t*)(Qn + (size_t)(qbase + tid) * 64);
        h8_t* dst = (h8_t*)(Qs + tid * QSTR);
#pragma unroll
        for (int i = 0; i < 8; ++i) dst[i] = src[i];
    }
    __syncthreads();

    int lane = tid & 63, wave = tid >> 6;
    int col = lane & 15, quad = lane >> 4;

    // A fragments: invariant across all keys -> load once.
    // A[m=lane&15][k=quad*8+j]; two k-steps cover C=64.
    h8_t af[4][2];
#pragma unroll
    for (int qt = 0; qt < 4; ++qt)
#pragma unroll
        for (int ks = 0; ks < 2; ++ks)
            af[qt][ks] = *(const h8_t*)(Qs + (wave * 64 + qt * 16 + col) * QSTR + ks * 32 + quad * 8);

    float l[4][4], su[4][4], sv[4][4];
#pragma unroll
    for (int qt = 0; qt < 4; ++qt)
#pragma unroll
        for (int r = 0; r < 4; ++r) { l[qt][r] = 0.f; su[qt][r] = 0.f; sv[qt][r] = 0.f; }

    const _Float16* Kg = Kn + ((size_t)b * HWPX + kbase) * 64;

    for (int st = 0; st < 8; ++st) {            // 8 subtiles of 64 keys
        __syncthreads();
        {   // stage 64 keys x 64 ch: thread t -> key t>>2, 16-half part t&3 (coalesced 32B/thread)
            int key = tid >> 2, part = tid & 3;
            const h8_t* src = (const h8_t*)(Kg + ((size_t)(st * 64 + key)) * 64 + part * 16);
            h8_t x0 = src[0], x1 = src[1];
            h8_t* d = (h8_t*)(Ks + key * QSTR + part * 16);
            d[0] = x0; d[1] = x1;
        }
        __syncthreads();

#pragma unroll
        for (int nt = 0; nt < 4; ++nt) {        // 4 key tiles of 16
            const _Float16* krow = Ks + (nt * 16 + col) * QSTR + quad * 8;
            h8_t b0 = *(const h8_t*)(krow);
            h8_t b1 = *(const h8_t*)(krow + 32);
            int kg = kbase + st * 64 + nt * 16; // 16-aligned: tile never crosses an image row
            float vf = (float)(kg >> 8);
            float uf = (float)((kg & 255) + col);
#pragma unroll
            for (int qt = 0; qt < 4; ++qt) {
                f4_t acc = {0.f, 0.f, 0.f, 0.f};
                acc = __builtin_amdgcn_mfma_f32_16x16x32_f16(af[qt][0], b0, acc, 0, 0, 0);
                acc = __builtin_amdgcn_mfma_f32_16x16x32_f16(af[qt][1], b1, acc, 0, 0, 0);
#pragma unroll
                for (int r = 0; r < 4; ++r) {
                    float warg = fmaf(acc[r], 144.26950408889634f, -144.26950408889634f);
                    float wexp = exp2f(warg);
                    l[qt][r] += wexp;
                    su[qt][r] = fmaf(wexp, uf, su[qt][r]);
                    sv[qt][r] = fmaf(wexp, vf, sv[qt][r]);
                }
            }
        }
    }

    // butterfly-reduce across the 16 cols (keys) of each quad group, then atomics
#pragma unroll
    for (int qt = 0; qt < 4; ++qt)
#pragma unroll
        for (int r = 0; r < 4; ++r) {
            float a = l[qt][r], x = su[qt][r], y = sv[qt][r];
#pragma unroll
            for (int m = 1; m < 16; m <<= 1) {
                a += __shfl_xor(a, m, 64);
                x += __shfl_xor(x, m, 64);
                y += __shfl_xor(y, m, 64);
            }
            if (col == 0) {
                int q = qbase + wave * 64 + qt * 16 + quad * 4 + r;
                atomicAdd(&partials[q * 3 + 0], a);
                atomicAdd(&partials[q * 3 + 1], x);
                atomicAdd(&partials[q * 3 + 2], y);
            }
        }
}

// ---------------- Kernel 3: finalize ----------------
__global__ __launch_bounds__(256) void k_final(
    const float* __restrict__ partials, const float* __restrict__ kscores,
    float* __restrict__ out, int out_size)
{
    int idx = blockIdx.x * 256 + threadIdx.x;
    if (idx >= out_size) return;
    if (idx < 3072) {
        // pseudo_coords (6,256,2): q = idx>>1 matches (b*3+w)*256+n ordering
        int q = idx >> 1;
        float l = partials[q * 3 + 0];
        float s = partials[q * 3 + 1 + (idx & 1)];
        out[idx] = s / l;
    } else if (idx < 4608) {
        // keypoint_scores[tgt_ids]: frames {1,2,3,5,6,7}
        int i = idx - 3072;
        int j = i >> 8, n = i & 255;
        int frame = j + 1 + (j / 3);
        out[idx] = kscores[frame * 256 + n];
    } else if (idx < 4620) {
        int i = idx - 4608;
        if (i < 6) out[idx] = (float)(i + 1 + i / 3);       // tgt_ids 1,2,3,5,6,7
        else { int j = i - 6; out[idx] = (float)((j / 3) * 4); } // src_ids 0,0,0,4,4,4
    }
}

extern "C" void kernel_launch(void* const* d_in, const int* in_sizes, int n_in,
                              void* d_out, int out_size, void* d_ws, size_t ws_size,
                              hipStream_t stream) {
    const float* kp_scores = (const float*)d_in[0];   // (8,1,256)
    const float* kp_desc   = (const float*)d_in[1];   // (8,64,256)
    const float* dense     = (const float*)d_in[2];   // (8,64,256,256)
    // d_in[3] keypoint_coords unused by the reference outputs

    _Float16* Qn = (_Float16*)d_ws;                                   // 1536*64 halves
    _Float16* Kn = (_Float16*)((char*)d_ws + 196608);                 // 2*65536*64 halves
    float* partials = (float*)((char*)d_ws + 196608 + 16777216);      // 1536*3 floats

    hipLaunchKernelGGL(k_norm, dim3(518), dim3(256), 0, stream,
                       dense, kp_desc, Qn, Kn, partials);
    hipLaunchKernelGGL(k_attn, dim3(128, 3, 2), dim3(256), 0, stream,
                       Qn, Kn, partials);
    hipLaunchKernelGGL(k_final, dim3(19), dim3(256), 0, stream,
                       partials, kp_scores, (float*)d_out, out_size);
}